// Round 8
// baseline (249.853 us; speedup 1.0000x reference)
//
#include <hip/hip_runtime.h>
#include <hip/hip_bf16.h>

// out[b,o] = sum_n relu( (s[b]-v[n]) . W[n,o,:] + bias[n,o] )
//          = sum_n relu( s[b].W[n,o,:] + c[n,o] ),  c[n,o] = bias[n,o] - v[n].W[n,o,:]
//
// prep: per-(n,ob) LDS transpose. Reads W coalesced, converts bf16, stages in
//   XOR-swizzled LDS, computes c from the slab, writes Wswz in FRAGMENT ORDER:
//   1KB chunk per (n,ob,ks,og); lane l holds o=ob*64+og*32+(l&31), k=ks*16+(l>>5)*8.
// main: 32x32x16 MFMA. A staged once in LDS (kc^(row&15) swizzle). bq loads are
//   now perfectly coalesced 1KB streams (r7's 32-line gather was ~131k cy/CU of
//   TA work = the whole MFMA budget -- that was the 34% MfmaUtil wall).
// fused: fp32-W fallback if ws too small.

typedef __attribute__((ext_vector_type(8)))  short bf16x8;
typedef __attribute__((ext_vector_type(4)))  float f32x4;
typedef __attribute__((ext_vector_type(16))) float f32x16;

constexpr int B   = 1024;
constexpr int N   = 64;
constexpr int D   = 512;
constexpr int OUT = 2048;

constexpr int BM  = 128;    // rows per block
constexpr int BO  = 64;     // cols per block: 2 o-groups x 32
constexpr int TPB = 512;    // 8 waves

static __device__ __forceinline__ unsigned short f2bf(float f) {
    unsigned int u = __builtin_bit_cast(unsigned int, f);
    u += 0x7FFFu + ((u >> 16) & 1u);
    return (unsigned short)(u >> 16);
}

static __device__ __forceinline__ float bf2f(unsigned short u) {
    unsigned int x = ((unsigned int)u) << 16;
    return __builtin_bit_cast(float, x);
}

static __device__ __forceinline__ bf16x8 cvt8(float4 a, float4 b) {
    bf16x8 r;
    r[0] = (short)f2bf(a.x); r[1] = (short)f2bf(a.y);
    r[2] = (short)f2bf(a.z); r[3] = (short)f2bf(a.w);
    r[4] = (short)f2bf(b.x); r[5] = (short)f2bf(b.y);
    r[6] = (short)f2bf(b.z); r[7] = (short)f2bf(b.w);
    return r;
}

// ---------------- prep: Wswz (fragment-order) + c, via LDS transpose ----------------
// grid = N * 32 blocks (one per (n, ob) slab of 64 o-rows x 512 k), 256 threads.
__global__ __launch_bounds__(256) void prep_kernel(const float* __restrict__ W,
                                                   const float* __restrict__ V,
                                                   const float* __restrict__ bias,
                                                   unsigned short* __restrict__ Wswz,
                                                   float* __restrict__ c) {
    __shared__ unsigned short L[64 * 512];   // 64 KiB, swizzled: kc ^ (row&15)

    const int nb = blockIdx.x;
    const int n  = nb >> 5;          // 0..63
    const int ob = nb & 31;          // 0..31
    const int t  = threadIdx.x;

    // ---- stage slab: W[n][ob*64 + r][k], coalesced fp32 reads -> bf16 LDS ----
    #pragma unroll
    for (int i = 0; i < 16; ++i) {
        const int cid = i * 256 + t;         // 4096 chunks of 8 elems
        const int r   = cid >> 6;            // 0..63
        const int kc  = cid & 63;            // 0..63
        const float4* wp = reinterpret_cast<const float4*>(
            W + ((size_t)n * OUT + ob * 64 + r) * D + kc * 8);
        bf16x8 v8 = cvt8(wp[0], wp[1]);
        *reinterpret_cast<bf16x8*>(&L[r * 512 + ((kc ^ (r & 15)) * 8)]) = v8;
    }
    __syncthreads();

    // ---- c[n, ob*64 + r] = bias - dot(v[n], row r of slab) ----
    if (t < 64) {
        const int r = t;
        float s = 0.f;
        #pragma unroll 8
        for (int kc = 0; kc < 64; ++kc) {
            bf16x8 wv = *reinterpret_cast<const bf16x8*>(&L[r * 512 + ((kc ^ (r & 15)) * 8)]);
            const float4 va = *reinterpret_cast<const float4*>(V + (size_t)n * D + kc * 8);
            const float4 vb = *reinterpret_cast<const float4*>(V + (size_t)n * D + kc * 8 + 4);
            s += bf2f((unsigned short)wv[0]) * va.x + bf2f((unsigned short)wv[1]) * va.y
               + bf2f((unsigned short)wv[2]) * va.z + bf2f((unsigned short)wv[3]) * va.w
               + bf2f((unsigned short)wv[4]) * vb.x + bf2f((unsigned short)wv[5]) * vb.y
               + bf2f((unsigned short)wv[6]) * vb.z + bf2f((unsigned short)wv[7]) * vb.w;
        }
        const int o = ob * 64 + r;
        c[n * OUT + o] = bias[n * OUT + o] - s;
    }

    // ---- write fragment-order chunks, coalesced 1KB/wave ----
    // chunk(n,ob,ks,og): index = (n*32+ob)*64 + ks*2 + og; lane l -> 16B at
    // row = og*32 + (l&31), k = ks*16 + (l>>5)*8.
    const size_t obase = ((size_t)(n * 32 + ob) * 64) * 512;
    #pragma unroll
    for (int i = 0; i < 16; ++i) {
        const int cid  = i * 256 + t;        // (ks*2+og)*64 + lane
        const int lane = cid & 63;
        const int og   = (cid >> 6) & 1;
        const int ks   = cid >> 7;
        const int row  = og * 32 + (lane & 31);
        const int kc   = ks * 2 + (lane >> 5);
        bf16x8 v8 = *reinterpret_cast<const bf16x8*>(&L[row * 512 + ((kc ^ (row & 15)) * 8)]);
        *reinterpret_cast<bf16x8*>(&Wswz[obase + (size_t)(cid >> 6) * 512 + lane * 8]) = v8;
    }
}

// ---------------- main: 32x32x16 MFMA GEMM + relu + n-sum ----------------
__global__ __launch_bounds__(TPB) void main_kernel(const float* __restrict__ S,
                                                   const unsigned short* __restrict__ Wswz,
                                                   const float* __restrict__ C,
                                                   float* __restrict__ out) {
    // A-tile: 128 rows x 512 k bf16, XOR-swizzled in 16B chunks: kc ^ (row&15).
    __shared__ unsigned short As[BM * D];   // 128 KiB

    const int t    = threadIdx.x;
    const int lane = t & 63;
    const int w    = t >> 6;          // 0..7
    const int og   = w & 1;           // o-group (32 cols)
    const int ng   = w >> 1;          // n-quarter (16 n each)
    const int oc   = lane & 31;
    const int hi   = lane >> 5;       // k-half selector (A and B)
    const int ob   = blockIdx.x;      // 0..31
    const int bm0  = blockIdx.y * BM;
    const int ocol = ob * BO + og * 32 + oc;

    // ---- stage A = S[bm0:bm0+BM, :] as bf16 (once per block) ----
    #pragma unroll
    for (int i = 0; i < (BM * D / 8) / TPB; ++i) {   // 16 iters
        int cid = i * TPB + t;
        int row = cid >> 6;            // 64 chunks per row
        int kc  = cid & 63;
        const float4* sp = reinterpret_cast<const float4*>(S + (size_t)(bm0 + row) * D + kc * 8);
        bf16x8 val = cvt8(sp[0], sp[1]);
        *reinterpret_cast<bf16x8*>(&As[row * D + ((kc ^ (row & 15)) * 8)]) = val;
    }
    __syncthreads();

    f32x16 oacc[4];
    #pragma unroll
    for (int mi = 0; mi < 4; ++mi)
        #pragma unroll
        for (int r = 0; r < 16; ++r) oacc[mi][r] = 0.f;

    for (int nc = 0; nc < 8; ++nc) {
        const int n0 = ng * 16 + nc * 2;

        f32x16 pre[2][4];
        #pragma unroll
        for (int j = 0; j < 2; ++j)
            #pragma unroll
            for (int mi = 0; mi < 4; ++mi)
                #pragma unroll
                for (int r = 0; r < 16; ++r) pre[j][mi][r] = 0.f;

        // fragment-order W: coalesced 1KB per wave-load, SGPR base + imm offsets.
        const unsigned short* wb0 =
            Wswz + ((size_t)(n0 * 32 + ob) * 64 + og) * 512 + lane * 8;
        const unsigned short* wb1 = wb0 + (size_t)2048 * 512;   // n0+1

        #pragma unroll 4
        for (int ks = 0; ks < 32; ++ks) {           // K-steps of 16
            bf16x8 bq0 = *reinterpret_cast<const bf16x8*>(wb0 + ks * 1024);
            bf16x8 bq1 = *reinterpret_cast<const bf16x8*>(wb1 + ks * 1024);
            const int kc2 = ks * 2 + hi;            // 16B chunk index along k
            #pragma unroll
            for (int mi = 0; mi < 4; ++mi) {
                const int row = mi * 32 + oc;       // A-frag row = lane&31
                bf16x8 aq = *reinterpret_cast<const bf16x8*>(
                    &As[row * D + ((kc2 ^ (row & 15)) * 8)]);
                pre[0][mi] = __builtin_amdgcn_mfma_f32_32x32x16_bf16(aq, bq0, pre[0][mi], 0, 0, 0);
                pre[1][mi] = __builtin_amdgcn_mfma_f32_32x32x16_bf16(aq, bq1, pre[1][mi], 0, 0, 0);
            }
        }

        #pragma unroll
        for (int j = 0; j < 2; ++j) {
            const float cv = C[(n0 + j) * OUT + ocol];
            #pragma unroll
            for (int mi = 0; mi < 4; ++mi)
                #pragma unroll
                for (int r = 0; r < 16; ++r)
                    oacc[mi][r] += fmaxf(pre[j][mi][r] + cv, 0.f);
        }
    }

    // ---- 4-way cross n-quarter reduction through LDS, then store ----
    __syncthreads();                      // everyone done reading As
    float* red = reinterpret_cast<float*>(As);
    if (ng != 0) {
        const int slab = ((ng - 1) * 2 + og) * 4096;
        #pragma unroll
        for (int mi = 0; mi < 4; ++mi) {
            #pragma unroll
            for (int rg = 0; rg < 4; ++rg) {
                f32x4 v = {oacc[mi][rg * 4 + 0], oacc[mi][rg * 4 + 1],
                           oacc[mi][rg * 4 + 2], oacc[mi][rg * 4 + 3]};
                *reinterpret_cast<f32x4*>(&red[slab + (mi * 4 + rg) * 256 + lane * 4]) = v;
            }
        }
    }
    __syncthreads();
    if (ng == 0) {
        #pragma unroll
        for (int mi = 0; mi < 4; ++mi) {
            #pragma unroll
            for (int rg = 0; rg < 4; ++rg) {
                f32x4 sum = {oacc[mi][rg * 4 + 0], oacc[mi][rg * 4 + 1],
                             oacc[mi][rg * 4 + 2], oacc[mi][rg * 4 + 3]};
                #pragma unroll
                for (int s = 0; s < 3; ++s) {
                    const int slab = (s * 2 + og) * 4096;
                    f32x4 o2 = *reinterpret_cast<const f32x4*>(
                        &red[slab + (mi * 4 + rg) * 256 + lane * 4]);
                    #pragma unroll
                    for (int q = 0; q < 4; ++q) sum[q] += o2[q];
                }
                // C/D layout (m74/m101): col = lane&31, row = (r&3)+8*(r>>2)+4*hi
                #pragma unroll
                for (int q = 0; q < 4; ++q) {
                    const int row = bm0 + mi * 32 + q + 8 * rg + 4 * hi;
                    out[(size_t)row * OUT + ocol] = sum[q];
                }
            }
        }
    }
}

// ---------------- fallback: fused fp32-W kernel (r2-proven) ----------------
__global__ __launch_bounds__(512) void fused_kernel(const float* __restrict__ S,
                                                    const float* __restrict__ W,
                                                    const float* __restrict__ V,
                                                    const float* __restrict__ bias,
                                                    float* __restrict__ out) {
    __shared__ unsigned short As3[128 * D];

    const int t    = threadIdx.x;
    const int lane = t & 63;
    const int w    = t >> 6;
    const int og   = w & 3;
    const int ngh  = w >> 2;
    const int l15  = lane & 15;
    const int lg   = lane >> 4;
    const int ob0  = blockIdx.x * 64;
    const int bm0  = blockIdx.y * 128;
    const int ocol = ob0 + og * 16 + l15;

    #pragma unroll
    for (int i = 0; i < (128 * D / 8) / 512; ++i) {
        int cid = i * 512 + t;
        int row = cid >> 6;
        int kc  = cid & 63;
        const float4* sp = reinterpret_cast<const float4*>(S + (size_t)(bm0 + row) * D + kc * 8);
        bf16x8 val = cvt8(sp[0], sp[1]);
        *reinterpret_cast<bf16x8*>(&As3[row * D + ((kc ^ (row & 7)) * 8)]) = val;
    }
    __syncthreads();

    f32x4 oacc[8];
    #pragma unroll
    for (int mi = 0; mi < 8; ++mi) oacc[mi] = (f32x4){0.f, 0.f, 0.f, 0.f};

    const int kofs = lg * 8;

    for (int nc = 0; nc < 8; ++nc) {
        const int n0 = ngh * 32 + nc * 4;

        f32x4 pre[4][8];
        #pragma unroll
        for (int j = 0; j < 4; ++j)
            #pragma unroll
            for (int mi = 0; mi < 8; ++mi) pre[j][mi] = (f32x4){0.f, 0.f, 0.f, 0.f};

        float cacc[4] = {0.f, 0.f, 0.f, 0.f};

        const float* wbase = W + ((size_t)n0 * OUT + ocol) * D + kofs;
        const float* vbase = V + (size_t)n0 * D + kofs;

        #pragma unroll 2
        for (int ks = 0; ks < 16; ++ks) {
            bf16x8 bq[4];
            #pragma unroll
            for (int j = 0; j < 4; ++j) {
                const float* wr = wbase + (size_t)j * (OUT * D) + ks * 32;
                float4 wa = *reinterpret_cast<const float4*>(wr);
                float4 wb = *reinterpret_cast<const float4*>(wr + 4);
                const float* vr = vbase + (size_t)j * D + ks * 32;
                float4 va = *reinterpret_cast<const float4*>(vr);
                float4 vb = *reinterpret_cast<const float4*>(vr + 4);
                cacc[j] += wa.x * va.x + wa.y * va.y + wa.z * va.z + wa.w * va.w
                         + wb.x * vb.x + wb.y * vb.y + wb.z * vb.z + wb.w * vb.w;
                bq[j] = cvt8(wa, wb);
            }
            const int kc = ks * 4 + lg;
            #pragma unroll
            for (int mi = 0; mi < 8; ++mi) {
                const int row = mi * 16 + l15;
                bf16x8 aq = *reinterpret_cast<const bf16x8*>(
                    &As3[row * D + ((kc ^ (row & 7)) * 8)]);
                pre[0][mi] = __builtin_amdgcn_mfma_f32_16x16x32_bf16(aq, bq[0], pre[0][mi], 0, 0, 0);
                pre[1][mi] = __builtin_amdgcn_mfma_f32_16x16x32_bf16(aq, bq[1], pre[1][mi], 0, 0, 0);
                pre[2][mi] = __builtin_amdgcn_mfma_f32_16x16x32_bf16(aq, bq[2], pre[2][mi], 0, 0, 0);
                pre[3][mi] = __builtin_amdgcn_mfma_f32_16x16x32_bf16(aq, bq[3], pre[3][mi], 0, 0, 0);
            }
        }

        #pragma unroll
        for (int j = 0; j < 4; ++j) {
            float cs = cacc[j];
            cs += __shfl_xor(cs, 16);
            cs += __shfl_xor(cs, 32);
            const float cv = bias[(n0 + j) * OUT + ocol] - cs;
            #pragma unroll
            for (int mi = 0; mi < 8; ++mi)
                #pragma unroll
                for (int r = 0; r < 4; ++r)
                    oacc[mi][r] += fmaxf(pre[j][mi][r] + cv, 0.f);
        }
    }

    __syncthreads();
    float* red = reinterpret_cast<float*>(As3);
    if (ngh == 1) {
        #pragma unroll
        for (int mi = 0; mi < 8; ++mi)
            *reinterpret_cast<f32x4*>(&red[(og * 8 + mi) * 256 + lane * 4]) = oacc[mi];
    }
    __syncthreads();
    if (ngh == 0) {
        #pragma unroll
        for (int mi = 0; mi < 8; ++mi) {
            f32x4 o2 = *reinterpret_cast<const f32x4*>(&red[(og * 8 + mi) * 256 + lane * 4]);
            #pragma unroll
            for (int r = 0; r < 4; ++r) {
                int row = bm0 + mi * 16 + lg * 4 + r;
                out[(size_t)row * OUT + ocol] = oacc[mi][r] + o2[r];
            }
        }
    }
}

extern "C" void kernel_launch(void* const* d_in, const int* in_sizes, int n_in,
                              void* d_out, int out_size, void* d_ws, size_t ws_size,
                              hipStream_t stream) {
    const float* S    = (const float*)d_in[0];   // semantic_vec [B, D]
    const float* V    = (const float*)d_in[1];   // vertices     [N, D]
    const float* W    = (const float*)d_in[2];   // W            [N, OUT, D]
    const float* bias = (const float*)d_in[3];   // b            [N, OUT]
    float* out = (float*)d_out;                  // [B, OUT] f32

    const size_t wb_bytes = (size_t)N * OUT * D * sizeof(unsigned short); // 128 MiB
    const size_t c_bytes  = (size_t)N * OUT * sizeof(float);              // 512 KiB

    if (ws_size >= wb_bytes + c_bytes) {
        unsigned short* Wswz = (unsigned short*)d_ws;
        float*          c    = (float*)((char*)d_ws + wb_bytes);
        prep_kernel<<<dim3(N * 32), dim3(256), 0, stream>>>(W, V, bias, Wswz, c);
        main_kernel<<<dim3(OUT / BO, B / BM), dim3(TPB), 0, stream>>>(S, Wswz, c, out);
    } else {
        fused_kernel<<<dim3(OUT / 64, B / 128), dim3(512), 0, stream>>>(S, W, V, bias, out);
    }
}